// Round 6
// baseline (527.117 us; speedup 1.0000x reference)
//
#include <hip/hip_runtime.h>

// Double-sparse matvec: y = A @ (B @ x), ELL form.
// M=N=K=8192, NNZ=256 per row, BATCH=32, fp32 in/out.
//
// R16 = R15 (fused, fence-free barriers) + ONE structural change: overlap
// L3 staging with compute via a BATCH-SPLIT double buffer. R15's passes ran
// ~30us vs diag's 17.6us: each pass stages 512KB/CU from L3 (x16/bx16 are
// write-through fresh, no L2 copy) and the stage->barrier->compute structure
// serializes that ~12us/pass. Splitting the batch (2 halves x 16 cols) makes
// a segment 2048 rows x 32B = 64KB -> two buffers fit in 128KB LDS, with
// per-nnz work per half HALVED -> total VALU / LDS bytes / staged bytes all
// identical to R15. Pipeline: STAGE(next) -> COMPUTE(cur) -> syncthreads
// (vmcnt drain lands after compute covers the latency). 8 units per pass,
// statically unrolled (acc indexed by literal h only).
//
// Lane layout (per row): lane = q*2 + s.
//   s in [0,2): batch octet within the half -- 8 fp16 cols (16B) per lane
//   q in [0,32): owns consecutive nnz block j = q*8 .. q*8+7

#define NNZ     256
#define BATCH   32
#define ROWS    8192
#define SEGR    2048          // table rows per LDS buffer (32B each)
#define RPB     32            // rows per block
#define THREADS 512
#define BLOCKS  (ROWS / RPB)  // 256
#define BUFB    65536         // 64KB per buffer

typedef int      vi4 __attribute__((ext_vector_type(4)));
typedef float    vf4 __attribute__((ext_vector_type(4)));
typedef _Float16 vh2 __attribute__((ext_vector_type(2)));
typedef _Float16 vh8 __attribute__((ext_vector_type(8)));

union V8 { vh8 h8; vh2 h2[4]; unsigned u[4]; };

struct RowRegs { vi4 iv[4][2]; unsigned hh[4][8]; };

// fp32 -> fp16 broadcast-pair (both halves of a u32 hold the same fp16)
static __device__ __forceinline__ unsigned hpack(float f)
{
    const unsigned short u = __builtin_bit_cast(unsigned short, (_Float16)f);
    return ((unsigned)u << 16) | (unsigned)u;
}

// Load 4 rows' worth of idx/vals (this lane's 8-nnz q-block) into registers.
static __device__ __forceinline__ void load_rows(
    const int* __restrict__ idx, const float* __restrict__ vals,
    int r0, int q, RowRegs& R)
{
    #pragma unroll
    for (int t = 0; t < 4; ++t) {
        const vi4* i4 = (const vi4*)(idx  + (size_t)(r0 + t) * NNZ) + q * 2;
        const vf4* v4 = (const vf4*)(vals + (size_t)(r0 + t) * NNZ) + q * 2;
        vf4 vv[2];
        #pragma unroll
        for (int u = 0; u < 2; ++u) R.iv[t][u] = __builtin_nontemporal_load(i4 + u);
        #pragma unroll
        for (int u = 0; u < 2; ++u) vv[u]      = __builtin_nontemporal_load(v4 + u);
        #pragma unroll
        for (int u = 0; u < 2; ++u) {
            R.hh[t][4*u+0] = hpack(vv[u].x);
            R.hh[t][4*u+1] = hpack(vv[u].y);
            R.hh[t][4*u+2] = hpack(vv[u].z);
            R.hh[t][4*u+3] = hpack(vv[u].w);
        }
    }
}

// One nnz, branchless segment-membership (buffer holds 2048 rows x 32B):
//  in-segment : read the row's 16B slice for this s, pk_fma with bcast val
//  out-of-seg : uniform addr soffb (LDS broadcast, conflict-free), fma by 0.
static __device__ __forceinline__ void proc1(
    int k, unsigned bb, int p, const char* lb, int soffb, V8& a)
{
    const bool in = (((unsigned)k >> 11) == (unsigned)p);
    const int  ra = ((k & 2047) << 5) + soffb;
    const int  ad = in ? ra : soffb;
    V8 xv;
    xv.h8 = *(const vh8*)(lb + ad);
    const vh2 b2 = __builtin_bit_cast(vh2, in ? bb : 0u);
    a.h2[0] += b2 * xv.h2[0];
    a.h2[1] += b2 * xv.h2[1];
    a.h2[2] += b2 * xv.h2[2];
    a.h2[3] += b2 * xv.h2[3];
}

// Stage one 64KB unit (batch-half h, segment p) into a buffer.
// Global table rows are 64B; we take bytes [32h, 32h+32) of rows
// [p*2048, (p+1)*2048). LDS dst is linear (wave-uniform + lane*16, as
// global_load_lds requires); per-lane global src carries the h-stride.
// stdst = lds + buf + tid*16;  gt = (tid>>1)*64 + (tid&1)*16.
static __device__ __forceinline__ void stage_unit(
    const char* __restrict__ tbl, char* stdst, int h, int p, int gt)
{
    const char* gsrc = tbl + (size_t)p * (SEGR * 64) + h * 32 + gt;
    #pragma unroll
    for (int rnd = 0; rnd < 8; ++rnd) {
        __builtin_amdgcn_global_load_lds(
            (const __attribute__((address_space(1))) unsigned int*)(gsrc + rnd * 16384),
            (__attribute__((address_space(3))) unsigned int*)(stdst + rnd * 8192),
            16, 0, 0);
    }
}

// Process all 32 PROC slots of one (half, segment) unit from buffer lb.
static __device__ __forceinline__ void compute_unit(
    const RowRegs& R, const char* lb, int p, int soffb, V8 acc[4])
{
    #pragma unroll
    for (int t = 0; t < 4; ++t) {
        #pragma unroll
        for (int u = 0; u < 2; ++u) {
            proc1(R.iv[t][u].x, R.hh[t][4*u+0], p, lb, soffb, acc[t]);
            proc1(R.iv[t][u].y, R.hh[t][4*u+1], p, lb, soffb, acc[t]);
            proc1(R.iv[t][u].z, R.hh[t][4*u+2], p, lb, soffb, acc[t]);
            proc1(R.iv[t][u].w, R.hh[t][4*u+3], p, lb, soffb, acc[t]);
        }
    }
}

// One pass over a [ROWS][BATCH] fp16 table: 8 units (2 halves x 4 segments),
// double-buffered. STAGE(next) issues before COMPUTE(cur); __syncthreads'
// vmcnt(0) drain lands after compute has covered the load flight time.
static __device__ __forceinline__ void pass8(
    const RowRegs& R, const char* __restrict__ tbl, _Float16* lds,
    int tid, int gt, int soffb, V8 acc0[4], V8 acc1[4])
{
    char* st0 = (char*)lds + tid * 16;
    char* st1 = (char*)lds + BUFB + tid * 16;
    const char* lb0 = (const char*)lds;
    const char* lb1 = (const char*)lds + BUFB;

    stage_unit(tbl, st0, 0, 0, gt);
    __syncthreads();
    stage_unit(tbl, st1, 0, 1, gt); compute_unit(R, lb0, 0, soffb, acc0); __syncthreads();
    stage_unit(tbl, st0, 0, 2, gt); compute_unit(R, lb1, 1, soffb, acc0); __syncthreads();
    stage_unit(tbl, st1, 0, 3, gt); compute_unit(R, lb0, 2, soffb, acc0); __syncthreads();
    stage_unit(tbl, st0, 1, 0, gt); compute_unit(R, lb1, 3, soffb, acc0); __syncthreads();
    stage_unit(tbl, st1, 1, 1, gt); compute_unit(R, lb0, 0, soffb, acc1); __syncthreads();
    stage_unit(tbl, st0, 1, 2, gt); compute_unit(R, lb1, 1, soffb, acc1); __syncthreads();
    stage_unit(tbl, st1, 1, 3, gt); compute_unit(R, lb0, 2, soffb, acc1); __syncthreads();
                                    compute_unit(R, lb1, 3, soffb, acc1); __syncthreads();
}

// Manual grid barrier (R15 structure, fence-free; cross-barrier data goes
// through sc1 write-through stores). Counter zeroed by bar_init dispatch.
static __device__ __forceinline__ void gridbar(unsigned* bar, unsigned target)
{
    __syncthreads();                       // all block stores complete (vmcnt 0)
    if (threadIdx.x == 0) {
        __hip_atomic_fetch_add(bar, 1u, __ATOMIC_RELAXED,
                               __HIP_MEMORY_SCOPE_AGENT);
        while (__hip_atomic_load(bar, __ATOMIC_RELAXED,
                                 __HIP_MEMORY_SCOPE_AGENT) < target) {
            __builtin_amdgcn_s_sleep(16);
        }
    }
    __syncthreads();
}

// Write-through agent-scope store of one dword (visible at the coherence
// point once vmcnt drains; no L2 dirty state -> no fences needed).
static __device__ __forceinline__ void st_agent_u32(unsigned* p, unsigned v)
{
    __hip_atomic_store(p, v, __ATOMIC_RELAXED, __HIP_MEMORY_SCOPE_AGENT);
}

__global__ void bar_init(unsigned* bar)
{
    if (threadIdx.x == 0)
        __hip_atomic_store(bar, 0u, __ATOMIC_RELEASE, __HIP_MEMORY_SCOPE_AGENT);
}

__global__ __launch_bounds__(THREADS, 2) void fused_spmv(
    const float* __restrict__ x,       // [ROWS, BATCH] fp32
    const int*   __restrict__ a_idx,   // [ROWS, NNZ]
    const float* __restrict__ a_vals,  // [ROWS, NNZ]
    const int*   __restrict__ b_idx,   // [ROWS, NNZ]
    const float* __restrict__ b_vals,  // [ROWS, NNZ]
    _Float16*    __restrict__ x16,     // ws: [ROWS, BATCH] fp16
    _Float16*    __restrict__ bx16,    // ws: [ROWS, BATCH] fp16
    float*       __restrict__ out,     // [BATCH, ROWS] fp32
    unsigned*    __restrict__ bar)     // ws: grid barrier counter
{
    __shared__ __attribute__((aligned(16))) _Float16 lds[2 * BUFB / 2]; // 128KB

    const int tid   = threadIdx.x;
    const int wave  = tid >> 6;          // 0..7
    const int lane  = tid & 63;
    const int s     = lane & 1;          // batch octet within half
    const int q     = lane >> 1;         // nnz block of 8
    const int soffb = s * 16;            // byte offset within a 32B half-row
    const int gt    = ((tid >> 1) << 6) + ((tid & 1) << 4);  // staging src
    const int rbase = blockIdx.x * RPB;
    const int r0    = rbase + wave * 4;  // this wave's first row

    // ---- Phase A: b-rows prologue (cold HBM, issue first) + x convert ----
    RowRegs RB;
    load_rows(b_idx, b_vals, r0, q, RB);
    {
        const int gid = blockIdx.x * THREADS + tid;     // 2 f32 per thread
        const float2 v = ((const float2*)x)[gid];
        vh2 h; h.x = (_Float16)v.x; h.y = (_Float16)v.y;
        st_agent_u32((unsigned*)x16 + gid, __builtin_bit_cast(unsigned, h));
    }
    gridbar(bar, BLOCKS);                // x16 fully written, device-visible

    // ---- Phase B: bx = B @ x16 ----
    V8 acc0[4], acc1[4];
    #pragma unroll
    for (int t = 0; t < 4; ++t) {
        acc0[t].u[0] = acc0[t].u[1] = acc0[t].u[2] = acc0[t].u[3] = 0;
        acc1[t].u[0] = acc1[t].u[1] = acc1[t].u[2] = acc1[t].u[3] = 0;
    }
    pass8(RB, (const char*)x16, lds, tid, gt, soffb, acc0, acc1);

    // a-rows prologue NOW: latency hides under B-epilogue + barrier + C
    // staging; registers survive the grid barrier.
    RowRegs RA;
    load_rows(a_idx, a_vals, r0, q, RA);

    // B epilogue: widen, reduce across the 32 q-blocks, write bx16 rows
    #pragma unroll
    for (int t = 0; t < 4; ++t) {
        #pragma unroll
        for (int h = 0; h < 2; ++h) {
            float a32[8];
            #pragma unroll
            for (int j = 0; j < 8; ++j)
                a32[j] = (float)((h == 0) ? acc0[t].h8[j] : acc1[t].h8[j]);
            #pragma unroll
            for (int d = 2; d < 64; d <<= 1) {
                #pragma unroll
                for (int j = 0; j < 8; ++j) a32[j] += __shfl_xor(a32[j], d);
            }
            if (q == 0) {                // lanes 0,1: 16B each, sc1 stores
                V8 cv;
                #pragma unroll
                for (int j = 0; j < 8; ++j) cv.h8[j] = (_Float16)a32[j];
                unsigned* dp = (unsigned*)(bx16 + (size_t)(r0 + t) * BATCH)
                               + h * 8 + s * 4;
                #pragma unroll
                for (int w = 0; w < 4; ++w) st_agent_u32(dp + w, cv.u[w]);
            }
        }
    }
    gridbar(bar, 2 * BLOCKS);            // bx16 fully written, device-visible

    // ---- Phase C: out = A @ bx16 ----
    #pragma unroll
    for (int t = 0; t < 4; ++t) {
        acc0[t].u[0] = acc0[t].u[1] = acc0[t].u[2] = acc0[t].u[3] = 0;
        acc1[t].u[0] = acc1[t].u[1] = acc1[t].u[2] = acc1[t].u[3] = 0;
    }
    pass8(RA, (const char*)bx16, lds, tid, gt, soffb, acc0, acc1);

    // (pass8 ends with __syncthreads -> safe to reuse lds as the out tile)
    float* tile = (float*)lds;           // [32][33] padded
    #pragma unroll
    for (int t = 0; t < 4; ++t) {
        #pragma unroll
        for (int h = 0; h < 2; ++h) {
            float a32[8];
            #pragma unroll
            for (int j = 0; j < 8; ++j)
                a32[j] = (float)((h == 0) ? acc0[t].h8[j] : acc1[t].h8[j]);
            #pragma unroll
            for (int d = 2; d < 64; d <<= 1) {
                #pragma unroll
                for (int j = 0; j < 8; ++j) a32[j] += __shfl_xor(a32[j], d);
            }
            if (q == 0) {
                const int rl = wave * 4 + t;
                #pragma unroll
                for (int j = 0; j < 8; ++j)
                    tile[rl * 33 + h * 16 + s * 8 + j] = a32[j];
            }
        }
    }
    __syncthreads();
    // out[b*ROWS + rbase + rr]: each thread stores 2 consecutive rows
    {
        const int e  = tid * 2;          // 1024 elems total
        const int b  = e >> 5;           // 0..31
        const int rr = e & 31;           // even
        float2 v2;
        v2.x = tile[rr * 33 + b];
        v2.y = tile[(rr + 1) * 33 + b];
        *(float2*)(out + (size_t)b * ROWS + rbase + rr) = v2;
    }
}

extern "C" void kernel_launch(void* const* d_in, const int* in_sizes, int n_in,
                              void* d_out, int out_size, void* d_ws, size_t ws_size,
                              hipStream_t stream) {
    (void)in_sizes; (void)n_in; (void)out_size; (void)ws_size;
    // setup_inputs order: x, a_idx, a_vals, b_idx, b_vals
    const float* x      = (const float*)d_in[0];   // [N, BATCH]
    const int*   a_idx  = (const int*)  d_in[1];   // [M, NNZ]
    const float* a_vals = (const float*)d_in[2];   // [M, NNZ]
    const int*   b_idx  = (const int*)  d_in[3];   // [K, NNZ]
    const float* b_vals = (const float*)d_in[4];   // [K, NNZ]
    float*       out    = (float*)d_out;           // [BATCH, M] fp32

    _Float16* bx16 = (_Float16*)d_ws;                         // 512 KB
    _Float16* x16  = bx16 + (size_t)ROWS * BATCH;             // 512 KB
    unsigned* bar  = (unsigned*)((char*)d_ws +
                                 (size_t)2 * ROWS * BATCH * sizeof(_Float16));

    bar_init<<<dim3(1), dim3(64), 0, stream>>>(bar);
    fused_spmv<<<dim3(BLOCKS), dim3(THREADS), 0, stream>>>(
        x, a_idx, a_vals, b_idx, b_vals, x16, bx16, out, bar);
}

// Round 8
// 121.895 us; speedup vs baseline: 4.3244x; 4.3244x over previous
//
#include <hip/hip_runtime.h>

// Double-sparse matvec: y = A @ (B @ x), ELL form.
// M=N=K=8192, NNZ=256 per row, BATCH=32, fp32 in/out.
//
// R18 = R17 + ONE-LINE FIX: the binned compute read entl[t*NNZ + i] -- the
// entry lists of local rows 0..3 for EVERY wave (entl holds all 32 block
// rows). Correct local row is wave*4 + t. All other R17 logic re-audited
// clean (bin ranks bijective, offsets consistent, staging wave-uniform).
//
// Structure (3 plain dispatches, no grid barrier):
//   1. bin_cvt: x fp32->fp16 + counting-sort each row's 256 (idx,val) pairs
//      by segment (idx>>11) via wave ballots + LDS scatter. Output:
//      bent[r][256] u32 = (fp16val<<16 | u16idx), off[r] = 4xu16 offsets.
//   2/3. ell_spmv_bin: serialized LDS staging (4 x 128KB table segments,
//      proven R12/R15 pattern) + binned compute: per segment, iterate ONLY
//      that segment's entries -> zero membership tests, zero dummy ds_reads,
//      4x fewer inner iterations than the branchless R12 form.
//      LDS = 128KB table + 32KB entries = 160KB (1 block/CU).
//
// Lane layout (per row): lane = q*4 + s.
//   s in [0,4): batch octet -- 8 fp16 batch columns (16B) per lane
//   q in [0,16): strides the segment's entry list by 16

#define NNZ     256
#define BATCH   32
#define ROWS    8192
#define SEGR    2048          // table rows per segment
#define NSEG    4
#define RPB     32            // rows per spmv block
#define THREADS 512
#define BLOCKS  (ROWS / RPB)  // 256

typedef int      vi4 __attribute__((ext_vector_type(4)));
typedef float    vf4 __attribute__((ext_vector_type(4)));
typedef _Float16 vh2 __attribute__((ext_vector_type(2)));
typedef _Float16 vh8 __attribute__((ext_vector_type(8)));

union V8 { vh8 h8; vh2 h2[4]; unsigned u[4]; };

static __device__ __forceinline__ void gll16(const char* g, char* l)
{
    __builtin_amdgcn_global_load_lds(
        (const __attribute__((address_space(1))) unsigned int*)g,
        (__attribute__((address_space(3))) unsigned int*)l, 16, 0, 0);
}

// ---- Dispatch 1: convert x to fp16 AND bin both matrices by segment ----
// grid 1024 x 256 (4 waves/block). Wave wgid handles rows {wgid, wgid+4096}
// of B then of A. Per row: ballot-based stable counting sort into 4 bins.
__global__ __launch_bounds__(256) void bin_cvt(
    const float* __restrict__ x,
    const int*   __restrict__ a_idx, const float* __restrict__ a_vals,
    const int*   __restrict__ b_idx, const float* __restrict__ b_vals,
    _Float16* __restrict__ x16,
    unsigned* __restrict__ bentB, unsigned long long* __restrict__ offB,
    unsigned* __restrict__ bentA, unsigned long long* __restrict__ offA)
{
    __shared__ __attribute__((aligned(16))) unsigned sent[4][NNZ]; // 4KB

    const int tid  = threadIdx.x;
    const int wave = tid >> 6;
    const int lane = tid & 63;

    // x convert: exactly one element per thread (1024*256 == 8192*32)
    {
        const int gid = blockIdx.x * 256 + tid;
        x16[gid] = (_Float16)x[gid];
    }

    const unsigned long long lt = (1ull << lane) - 1ull;
    const int wgid = blockIdx.x * 4 + wave;          // 0..4095

    #pragma unroll
    for (int w = 0; w < 4; ++w) {
        const bool isB = (w < 2);
        const int  r   = wgid + (w & 1) * 4096;
        const int*   idx  = isB ? b_idx  : a_idx;
        const float* vals = isB ? b_vals : a_vals;
        unsigned*           bent = isB ? bentB : bentA;
        unsigned long long* off  = isB ? offB  : offA;

        const vi4 kk = __builtin_nontemporal_load(
            (const vi4*)(idx + (size_t)r * NNZ) + lane);
        const vf4 vv = __builtin_nontemporal_load(
            (const vf4*)(vals + (size_t)r * NNZ) + lane);

        // ranks: per entry slot j, bin = k>>11; stable rank = running bin
        // count + popcount of earlier lanes in this slot's ballot.
        unsigned c0 = 0, c1 = 0, c2 = 0, c3 = 0;
        int sg[4]; unsigned rk[4];
        #pragma unroll
        for (int j = 0; j < 4; ++j) {
            const int sgn = kk[j] >> 11;             // 0..3
            const unsigned long long m0 = __ballot(sgn == 0);
            const unsigned long long m1 = __ballot(sgn == 1);
            const unsigned long long m2 = __ballot(sgn == 2);
            const unsigned long long m3 = __ballot(sgn == 3);
            rk[j] = (sgn == 0) ? c0 + (unsigned)__popcll(m0 & lt)
                  : (sgn == 1) ? c1 + (unsigned)__popcll(m1 & lt)
                  : (sgn == 2) ? c2 + (unsigned)__popcll(m2 & lt)
                  :              c3 + (unsigned)__popcll(m3 & lt);
            sg[j] = sgn;
            c0 += (unsigned)__popcll(m0); c1 += (unsigned)__popcll(m1);
            c2 += (unsigned)__popcll(m2); c3 += (unsigned)__popcll(m3);
        }
        const unsigned b1 = c0, b2 = c0 + c1, b3 = c0 + c1 + c2;

        // scatter into per-wave LDS row buffer as (fp16val<<16 | u16 idx)
        #pragma unroll
        for (int j = 0; j < 4; ++j) {
            const unsigned base = (sg[j] == 0) ? 0u : (sg[j] == 1) ? b1
                                 : (sg[j] == 2) ? b2 : b3;
            const unsigned short hv =
                __builtin_bit_cast(unsigned short, (_Float16)vv[j]);
            sent[wave][base + rk[j]] =
                ((unsigned)hv << 16) | ((unsigned)kk[j] & 0xFFFFu);
        }
        __syncthreads();   // order ds_writes before readback (block-uniform)

        // coalesced write-out: 16B per lane
        const vi4 ob = *(const vi4*)&sent[wave][lane * 4];
        *(vi4*)(bent + (size_t)r * NNZ + lane * 4) = ob;
        if (lane == 0)
            off[r] = ((unsigned long long)b1 << 16) |
                     ((unsigned long long)b2 << 32) |
                     ((unsigned long long)b3 << 48);
        __syncthreads();
    }
}

// ---- Dispatches 2/3: binned ELL spmv, serialized LDS-staged segments ----
template <bool OUT16>
__global__ __launch_bounds__(THREADS) void ell_spmv_bin(
    const unsigned* __restrict__ bent,           // [ROWS, NNZ] u32 binned
    const unsigned long long* __restrict__ off,  // [ROWS] 4x u16 offsets
    const _Float16* __restrict__ src,            // [ROWS, BATCH] fp16 table
    _Float16* __restrict__ dst16,                // [ROWS, BATCH] (OUT16)
    float*    __restrict__ dst32)                // [BATCH, ROWS] (!OUT16)
{
    __shared__ __attribute__((aligned(16))) _Float16 table[SEGR * BATCH]; //128K
    __shared__ __attribute__((aligned(16))) unsigned entl[RPB * NNZ];     //32K

    const int tid   = threadIdx.x;
    const int wave  = tid >> 6;
    const int lane  = tid & 63;
    const int s     = lane & 3;
    const int q     = lane >> 2;
    const int soffb = s * 16;
    const int rbase = blockIdx.x * RPB;
    const int r0    = rbase + wave * 4;

    // stage this block's binned entries (32KB) + table segment 0 (128KB)
    {
        const char* ge = (const char*)(bent + (size_t)rbase * NNZ);
        #pragma unroll
        for (int u = 0; u < 4; ++u)
            gll16(ge + u * 8192 + tid * 16, (char*)entl + u * 8192 + tid * 16);
        const char* gs = (const char*)src;
        #pragma unroll
        for (int u = 0; u < 16; ++u)
            gll16(gs + u * 8192 + tid * 16, (char*)table + u * 8192 + tid * 16);
    }

    // per-row segment offsets (wave-uniform values)
    int nof[4][5];
    #pragma unroll
    for (int t = 0; t < 4; ++t) {
        const unsigned long long o = off[r0 + t];
        nof[t][0] = (int)(o & 0xFFFFull);
        nof[t][1] = (int)((o >> 16) & 0xFFFFull);
        nof[t][2] = (int)((o >> 32) & 0xFFFFull);
        nof[t][3] = (int)((o >> 48) & 0xFFFFull);
        nof[t][4] = NNZ;
    }

    V8 acc[4];
    #pragma unroll
    for (int t = 0; t < 4; ++t) {
        acc[t].u[0] = acc[t].u[1] = acc[t].u[2] = acc[t].u[3] = 0;
    }

    __syncthreads();                 // staged data ready

    #pragma unroll
    for (int p = 0; p < NSEG; ++p) {
        // compute: only this segment's entries; no membership tests.
        #pragma unroll
        for (int t = 0; t < 4; ++t) {
            const int n1 = nof[t][p + 1];
            #pragma unroll 2
            for (int i = nof[t][p] + q; i < n1; i += 16) {
                const unsigned e  = entl[(wave * 4 + t) * NNZ + i]; // FIXED
                const unsigned bb = (e & 0xFFFF0000u) | (e >> 16);
                V8 xv;
                xv.h8 = *(const vh8*)((const char*)table +
                                      ((e & 2047u) << 6) + soffb);
                const vh2 b2 = __builtin_bit_cast(vh2, bb);
                acc[t].h2[0] += b2 * xv.h2[0];
                acc[t].h2[1] += b2 * xv.h2[1];
                acc[t].h2[2] += b2 * xv.h2[2];
                acc[t].h2[3] += b2 * xv.h2[3];
            }
        }
        if (p < NSEG - 1) {
            __syncthreads();         // segment fully consumed
            const char* gs = (const char*)src + (size_t)(p + 1) * (SEGR * 64);
            #pragma unroll
            for (int u = 0; u < 16; ++u)
                gll16(gs + u * 8192 + tid * 16,
                      (char*)table + u * 8192 + tid * 16);
            __syncthreads();         // vmcnt drained before compute
        }
    }

    // epilogue: widen, reduce across the 16 q-groups, store
    #pragma unroll
    for (int t = 0; t < 4; ++t) {
        float a32[8];
        #pragma unroll
        for (int j = 0; j < 8; ++j) a32[j] = (float)acc[t].h8[j];
        #pragma unroll
        for (int d = 4; d < 64; d <<= 1) {
            #pragma unroll
            for (int j = 0; j < 8; ++j) a32[j] += __shfl_xor(a32[j], d);
        }
        if (OUT16) {
            if (q == 0) {            // lanes 0..3: 64B coalesced row
                vh8 h;
                #pragma unroll
                for (int j = 0; j < 8; ++j) h[j] = (_Float16)a32[j];
                *(vh8*)(dst16 + (size_t)(r0 + t) * BATCH + s * 8) = h;
            }
        } else {
            if (t == 0) __syncthreads();   // table reads done; reuse as tile
            float* tile = (float*)table;   // [32][33] padded
            if (q == 0) {
                const int rl = wave * 4 + t;
                #pragma unroll
                for (int j = 0; j < 8; ++j) tile[rl * 33 + s * 8 + j] = a32[j];
            }
        }
    }

    if (!OUT16) {
        __syncthreads();
        float* tile = (float*)table;
        // out[b*ROWS + rbase + rr]: each thread stores 2 consecutive rows
        const int e  = tid * 2;          // 1024 elems total
        const int b  = e >> 5;           // 0..31
        const int rr = e & 31;           // even
        float2 v2;
        v2.x = tile[rr * 33 + b];
        v2.y = tile[(rr + 1) * 33 + b];
        *(float2*)(dst32 + (size_t)b * ROWS + rbase + rr) = v2;
    }
}

extern "C" void kernel_launch(void* const* d_in, const int* in_sizes, int n_in,
                              void* d_out, int out_size, void* d_ws, size_t ws_size,
                              hipStream_t stream) {
    (void)in_sizes; (void)n_in; (void)out_size; (void)ws_size;
    // setup_inputs order: x, a_idx, a_vals, b_idx, b_vals
    const float* x      = (const float*)d_in[0];   // [N, BATCH]
    const int*   a_idx  = (const int*)  d_in[1];   // [M, NNZ]
    const float* a_vals = (const float*)d_in[2];   // [M, NNZ]
    const int*   b_idx  = (const int*)  d_in[3];   // [K, NNZ]
    const float* b_vals = (const float*)d_in[4];   // [K, NNZ]
    float*       out    = (float*)d_out;           // [BATCH, M] fp32

    char* w = (char*)d_ws;
    _Float16* x16   = (_Float16*)(w);                        // 512 KB
    _Float16* bx16  = (_Float16*)(w + (1u << 19));           // 512 KB
    unsigned* bentB = (unsigned*)(w + (1u << 20));           // 8 MB
    unsigned* bentA = (unsigned*)(w + 9 * (1u << 20));       // 8 MB
    unsigned long long* offB =
        (unsigned long long*)(w + 17 * (1u << 20));          // 64 KB
    unsigned long long* offA =
        (unsigned long long*)(w + 17 * (1u << 20) + (1u << 16));

    bin_cvt<<<dim3(1024), dim3(256), 0, stream>>>(
        x, a_idx, a_vals, b_idx, b_vals, x16, bentB, offB, bentA, offA);
    ell_spmv_bin<true ><<<dim3(BLOCKS), dim3(THREADS), 0, stream>>>(
        bentB, offB, x16, bx16, nullptr);
    ell_spmv_bin<false><<<dim3(BLOCKS), dim3(THREADS), 0, stream>>>(
        bentA, offA, bx16, nullptr, out);
}